// Round 3
// baseline (535.816 us; speedup 1.0000x reference)
//
#include <hip/hip_runtime.h>
#include <hip/hip_bf16.h>
#include <math.h>

typedef __attribute__((ext_vector_type(8))) short short8;
typedef __attribute__((ext_vector_type(4))) float floatx4;

#define B_ 8
#define C_ 256
#define N_ 4096
#define LOG2E 1.4426950408889634f

static __device__ __forceinline__ unsigned short f2bf(float f) {
  union { float f; unsigned int u; } v; v.f = f;
  unsigned int u = v.u;
  u += 0x7FFFu + ((u >> 16) & 1u);   // RNE
  return (unsigned short)(u >> 16);
}
static __device__ __forceinline__ float bf2f(unsigned short h) {
  union { unsigned int u; float f; } v; v.u = ((unsigned int)h) << 16; return v.f;
}

// ---------------- kernel 0: weight convert + ssq zero ----------------
__global__ void prep_kernel(const float* __restrict__ Wq, const float* __restrict__ Wk,
                            const float* __restrict__ Wv,
                            unsigned short* __restrict__ wqb, unsigned short* __restrict__ wkb,
                            unsigned short* __restrict__ wvb, float* __restrict__ ssq) {
  int t = blockIdx.x * 256 + threadIdx.x;
  if (t < 512) ssq[t] = 0.0f;
  if (t < 8192) { wqb[t] = f2bf(Wq[t]); wkb[t] = f2bf(Wk[t]); }
  int tv = t - 8192;
  if (tv >= 0 && tv < 65536) wvb[tv] = f2bf(Wv[tv]);
}

// ---------------- kernel 1: QKV GEMM, channel-split x2 ----------------
// half 0: V channels 0..127 + Q ; half 1: V channels 128..255 + K
__launch_bounds__(256, 4)
__global__ void qkv_kernel(const float* __restrict__ x,
                           const unsigned short* __restrict__ wqb,
                           const unsigned short* __restrict__ wkb,
                           const unsigned short* __restrict__ wvb,
                           const float* __restrict__ bq, const float* __restrict__ bk,
                           const float* __restrict__ bv,
                           unsigned short* __restrict__ qbf, unsigned short* __restrict__ kbf,
                           unsigned short* __restrict__ vbf, float* __restrict__ ssq) {
  int b = blockIdx.x & 7;
  int nblk = (blockIdx.x >> 3) & 63;
  int half = blockIdx.x >> 9;
  int w = threadIdx.x >> 6, lane = threadIdx.x & 63;
  int r = lane & 15, g = lane >> 4;
  int n0 = nblk * 64 + w * 16;

  // B fragments from x: B[k=c][col=n], lane: col=r, k = g*8+j (per 32-k step)
  short8 xf[8];
  #pragma unroll
  for (int ks = 0; ks < 8; ++ks) {
    #pragma unroll
    for (int j = 0; j < 8; ++j) {
      int c = ks * 32 + g * 8 + j;
      float v = x[((size_t)(b * C_ + c) << 12) + n0 + r];
      ((unsigned short*)&xf[ks])[j] = f2bf(v);
    }
  }
  floatx4 zero = {0.f, 0.f, 0.f, 0.f};

  // ---- V tiles (8 per half) ----
  #pragma unroll 2
  for (int ot = half * 8; ot < half * 8 + 8; ++ot) {
    floatx4 acc = zero;
    #pragma unroll
    for (int ks = 0; ks < 8; ++ks) {
      short8 af = *(const short8*)&wvb[(ot * 16 + r) * 256 + ks * 32 + g * 8];
      acc = __builtin_amdgcn_mfma_f32_16x16x32_bf16(af, xf[ks], acc, 0, 0, 0);
    }
    #pragma unroll
    for (int rr = 0; rr < 4; ++rr) {
      int oc = ot * 16 + g * 4 + rr;
      vbf[((size_t)(b * C_ + oc) << 12) + n0 + r] = f2bf(acc[rr] + bv[oc]);
    }
  }
  // ---- Q (half 0) or K (half 1), 2 tiles ----
  const unsigned short* wb = half ? wkb : wqb;
  const float* bias = half ? bk : bq;
  unsigned short* dst = half ? kbf : qbf;
  int sbase = half ? 256 : 0;
  #pragma unroll 2
  for (int ot = 0; ot < 2; ++ot) {
    floatx4 acc = zero;
    #pragma unroll
    for (int ks = 0; ks < 8; ++ks) {
      short8 af = *(const short8*)&wb[(ot * 16 + r) * 256 + ks * 32 + g * 8];
      acc = __builtin_amdgcn_mfma_f32_16x16x32_bf16(af, xf[ks], acc, 0, 0, 0);
    }
    #pragma unroll
    for (int rr = 0; rr < 4; ++rr) {
      int oc = ot * 16 + g * 4 + rr;
      float val = acc[rr] + bias[oc];
      dst[(size_t)(b * N_ + n0 + r) * 32 + oc] = f2bf(val);
      float s = val * val;               // reduce over the 16 n (lanes r)
      s += __shfl_xor(s, 1);
      s += __shfl_xor(s, 2);
      s += __shfl_xor(s, 4);
      s += __shfl_xor(s, 8);
      if (r == 0) atomicAdd(&ssq[sbase + b * 32 + oc], s);
    }
  }
}

// ---------------- kernel 2: in-place scale of Q,K ----------------
// Q additionally scaled by log2(e) so attention can use raw v_exp_f32 (exp2).
__global__ void scale_kernel(unsigned int* __restrict__ qw, unsigned int* __restrict__ kw,
                             const float* __restrict__ ssq, const float* __restrict__ temp) {
  int tt = blockIdx.x * 256 + threadIdx.x;   // 1,048,576 u32 total (q then k)
  int is_k = tt >> 19;
  int idx = tt & 0x7FFFF;
  unsigned int* ptr = is_k ? kw : qw;
  unsigned int v = ptr[idx];
  int c0 = (idx & 15) * 2;
  int b = idx >> 16;
  float invt = is_k ? 1.0f : LOG2E / (temp[0] + 1e-6f);
  float s0 = ssq[is_k * 256 + b * 32 + c0];
  float s1 = ssq[is_k * 256 + b * 32 + c0 + 1];
  float sc0 = invt / fmaxf(sqrtf(s0), 1e-12f);
  float sc1 = invt / fmaxf(sqrtf(s1), 1e-12f);
  unsigned short lo = f2bf(bf2f((unsigned short)(v & 0xFFFFu)) * sc0);
  unsigned short hi = f2bf(bf2f((unsigned short)(v >> 16)) * sc1);
  ptr[idx] = ((unsigned int)hi << 16) | lo;
}

// ---------------- kernel 3: one-pass attention, m-split x2 ----------------
// S' = S*log2e in [-log2e, 2*log2e]; P = exp2(S' - 2*log2e). No max tracking.
// Block: 32 query rows (2 m-tiles), full n-range. wave w = (mt=w&1, nh=w>>1):
// QK^T for m-tile mt over n-half nh; PV cv-slice w*64. Grid 1024 -> 4 blocks/CU.
__launch_bounds__(256, 4)
__global__ void attn_kernel(const unsigned short* __restrict__ qbf,
                            const unsigned short* __restrict__ kbf,
                            const unsigned short* __restrict__ vbf,
                            const float* __restrict__ x, const float* __restrict__ gamma,
                            float* __restrict__ out) {
  __shared__ unsigned short Plds[2][2][16][72];   // [buf][m-tile][m][n(64) pad 72]
  __shared__ float Lbc[2][2][16];                 // [nh][mt][r]
  int b = blockIdx.x & 7, mblk = blockIdx.x >> 3; // mblk in [0,128)
  int w = threadIdx.x >> 6, lane = threadIdx.x & 63;
  int r = lane & 15, g = lane >> 4;
  int mt = w & 1, nh = w >> 1;
  const unsigned short* qb = qbf + (size_t)b * N_ * 32;
  const unsigned short* kb = kbf + (size_t)b * N_ * 32;
  const unsigned short* vb = vbf + (size_t)b * C_ * N_;
  int m0 = mblk * 32 + mt * 16;
  int cvbase = w * 64;
  short8 qfrag = *(const short8*)&qb[(m0 + r) * 32 + g * 8];
  floatx4 zero = {0.f, 0.f, 0.f, 0.f};

  floatx4 acc[2][4];                              // [mt][ct] O^T accum (unnormalized)
  #pragma unroll
  for (int mtt = 0; mtt < 2; ++mtt)
    #pragma unroll
    for (int ct = 0; ct < 4; ++ct) acc[mtt][ct] = zero;
  float Lp = 0.0f;
  int diagnt = mblk >> 1;                         // n-tile containing this block's m rows
  int diagnh = mblk & 1;

  // preload K,V fragments for nt=0
  short8 kf[2], vfA[2][4], vfB[2][4];
  #pragma unroll
  for (int f = 0; f < 2; ++f)
    kf[f] = *(const short8*)&kb[(size_t)(nh * 32 + f * 16 + r) * 32 + g * 8];
  #pragma unroll
  for (int ks = 0; ks < 2; ++ks)
    #pragma unroll
    for (int ct = 0; ct < 4; ++ct)
      vfA[ks][ct] = *(const short8*)&vb[(size_t)(cvbase + ct * 16 + r) * N_ + ks * 32 + g * 8];

  auto body = [&](int nt, short8 (&vcur)[2][4], short8 (&vnxt)[2][4]) {
    int pb = nt & 1;
    int nb2 = ((nt + 1) & 63) * 64;               // wrap: last iter reloads tile 0 (unused)
    floatx4 s[2];
    #pragma unroll
    for (int f = 0; f < 2; ++f)
      s[f] = __builtin_amdgcn_mfma_f32_16x16x32_bf16(kf[f], qfrag, zero, 0, 0, 0);
    // K prefetch for nt+1 (kf dead after the MFMAs above)
    #pragma unroll
    for (int f = 0; f < 2; ++f)
      kf[f] = *(const short8*)&kb[(size_t)(nb2 + nh * 32 + f * 16 + r) * 32 + g * 8];
    if (nt == diagnt && nh == diagnh) {           // +I on the diagonal (log2e scale)
      int d = r - 4 * g;
      if (d >= 0 && d < 4) s[mt][d] += LOG2E;
    }
    // P = exp2(S'-2log2e), accumulate L, truncate-pack bf16 -> LDS
    #pragma unroll
    for (int f = 0; f < 2; ++f) {
      float p0 = __builtin_amdgcn_exp2f(s[f][0] - 2.0f * LOG2E);
      float p1 = __builtin_amdgcn_exp2f(s[f][1] - 2.0f * LOG2E);
      float p2 = __builtin_amdgcn_exp2f(s[f][2] - 2.0f * LOG2E);
      float p3 = __builtin_amdgcn_exp2f(s[f][3] - 2.0f * LOG2E);
      Lp += (p0 + p1) + (p2 + p3);
      uint2 uu;
      uu.x = (__float_as_uint(p1) & 0xFFFF0000u) | (__float_as_uint(p0) >> 16);
      uu.y = (__float_as_uint(p3) & 0xFFFF0000u) | (__float_as_uint(p2) >> 16);
      *(uint2*)&Plds[pb][mt][r][nh * 32 + f * 16 + 4 * g] = uu;
    }
    // V prefetch for nt+1 — issued before the barrier so latency hides under PV
    #pragma unroll
    for (int ks = 0; ks < 2; ++ks)
      #pragma unroll
      for (int ct = 0; ct < 4; ++ct)
        vnxt[ks][ct] = *(const short8*)&vb[(size_t)(cvbase + ct * 16 + r) * N_ + nb2 + ks * 32 + g * 8];
    __syncthreads();                              // P[pb] visible to all waves
    #pragma unroll
    for (int ks = 0; ks < 2; ++ks) {
      short8 pf[2];
      #pragma unroll
      for (int mtt = 0; mtt < 2; ++mtt)
        pf[mtt] = *(const short8*)&Plds[pb][mtt][r][ks * 32 + g * 8];
      #pragma unroll
      for (int ct = 0; ct < 4; ++ct)
        #pragma unroll
        for (int mtt = 0; mtt < 2; ++mtt)
          acc[mtt][ct] = __builtin_amdgcn_mfma_f32_16x16x32_bf16(vcur[ks][ct], pf[mtt], acc[mtt][ct], 0, 0, 0);
    }
  };
  #pragma unroll 1
  for (int nt = 0; nt < 64; nt += 2) { body(nt, vfA, vfB); body(nt + 1, vfB, vfA); }

  // column denominators: g-reduce in-wave, combine the two nh halves via LDS
  Lp += __shfl_xor(Lp, 16);
  Lp += __shfl_xor(Lp, 32);
  if (lane < 16) Lbc[nh][mt][lane] = Lp;
  __syncthreads();
  float linv[2];
  #pragma unroll
  for (int mtt = 0; mtt < 2; ++mtt)
    linv[mtt] = 1.0f / (Lbc[0][mtt][r] + Lbc[1][mtt][r]);

  // epilogue: out = gamma * (O/L) + x
  float gam = gamma[0];
  #pragma unroll
  for (int mtt = 0; mtt < 2; ++mtt)
    #pragma unroll
    for (int ct = 0; ct < 4; ++ct)
      #pragma unroll
      for (int rr = 0; rr < 4; ++rr) {
        int cv = cvbase + ct * 16 + g * 4 + rr;
        int m = mblk * 32 + mtt * 16 + r;
        size_t idx = ((size_t)(b * C_ + cv) << 12) + m;
        out[idx] = gam * acc[mtt][ct][rr] * linv[mtt] + x[idx];
      }
}

extern "C" void kernel_launch(void* const* d_in, const int* in_sizes, int n_in,
                              void* d_out, int out_size, void* d_ws, size_t ws_size,
                              hipStream_t stream) {
  (void)in_sizes; (void)n_in; (void)out_size; (void)ws_size;
  const float* x    = (const float*)d_in[0];
  const float* Wq   = (const float*)d_in[1];
  const float* bq   = (const float*)d_in[2];
  const float* Wk   = (const float*)d_in[3];
  const float* bk   = (const float*)d_in[4];
  const float* Wv   = (const float*)d_in[5];
  const float* bv   = (const float*)d_in[6];
  const float* gam  = (const float*)d_in[7];
  const float* temp = (const float*)d_in[8];
  float* out = (float*)d_out;

  char* ws = (char*)d_ws;
  unsigned short* vbf = (unsigned short*)ws;                       // 16 MB
  unsigned short* qbf = (unsigned short*)(ws + (16u << 20));       // 2 MB
  unsigned short* kbf = (unsigned short*)(ws + (18u << 20));       // 2 MB
  unsigned short* wqb = (unsigned short*)(ws + (20u << 20));       // 16 KB
  unsigned short* wkb = wqb + 8192;                                // 16 KB
  unsigned short* wvb = wkb + 8192;                                // 128 KB
  float* ssq = (float*)(wvb + 65536);                              // 2 KB

  prep_kernel<<<dim3(288), dim3(256), 0, stream>>>(Wq, Wk, Wv, wqb, wkb, wvb, ssq);
  qkv_kernel<<<dim3(1024), dim3(256), 0, stream>>>(x, wqb, wkb, wvb, bq, bk, bv, qbf, kbf, vbf, ssq);
  scale_kernel<<<dim3(4096), dim3(256), 0, stream>>>((unsigned int*)qbf, (unsigned int*)kbf, ssq, temp);
  attn_kernel<<<dim3(1024), dim3(256), 0, stream>>>(qbf, kbf, vbf, x, gam, out);
}

// Round 4
// 354.361 us; speedup vs baseline: 1.5121x; 1.5121x over previous
//
#include <hip/hip_runtime.h>
#include <hip/hip_bf16.h>
#include <math.h>

typedef __attribute__((ext_vector_type(8))) short short8;
typedef __attribute__((ext_vector_type(4))) float floatx4;

#define B_ 8
#define C_ 256
#define N_ 4096
#define LOG2E 1.4426950408889634f

static __device__ __forceinline__ unsigned short f2bf(float f) {
  union { float f; unsigned int u; } v; v.f = f;
  unsigned int u = v.u;
  u += 0x7FFFu + ((u >> 16) & 1u);   // RNE
  return (unsigned short)(u >> 16);
}
static __device__ __forceinline__ float bf2f(unsigned short h) {
  union { unsigned int u; float f; } v; v.u = ((unsigned int)h) << 16; return v.f;
}

// ---------------- kernel 0: weight convert + ssq zero ----------------
__global__ void prep_kernel(const float* __restrict__ Wq, const float* __restrict__ Wk,
                            const float* __restrict__ Wv,
                            unsigned short* __restrict__ wqb, unsigned short* __restrict__ wkb,
                            unsigned short* __restrict__ wvb, float* __restrict__ ssq) {
  int t = blockIdx.x * 256 + threadIdx.x;
  if (t < 512) ssq[t] = 0.0f;
  if (t < 8192) { wqb[t] = f2bf(Wq[t]); wkb[t] = f2bf(Wk[t]); }
  int tv = t - 8192;
  if (tv >= 0 && tv < 65536) wvb[tv] = f2bf(Wv[tv]);
}

// ---------------- kernel 1: QKV GEMM, channel-split x2 ----------------
// half 0: V channels 0..127 + Q ; half 1: V channels 128..255 + K
__launch_bounds__(256, 4)
__global__ void qkv_kernel(const float* __restrict__ x,
                           const unsigned short* __restrict__ wqb,
                           const unsigned short* __restrict__ wkb,
                           const unsigned short* __restrict__ wvb,
                           const float* __restrict__ bq, const float* __restrict__ bk,
                           const float* __restrict__ bv,
                           unsigned short* __restrict__ qbf, unsigned short* __restrict__ kbf,
                           unsigned short* __restrict__ vbf, float* __restrict__ ssq) {
  int b = blockIdx.x & 7;
  int nblk = (blockIdx.x >> 3) & 63;
  int half = blockIdx.x >> 9;
  int w = threadIdx.x >> 6, lane = threadIdx.x & 63;
  int r = lane & 15, g = lane >> 4;
  int n0 = nblk * 64 + w * 16;

  // B fragments from x: B[k=c][col=n], lane: col=r, k = g*8+j (per 32-k step)
  short8 xf[8];
  #pragma unroll
  for (int ks = 0; ks < 8; ++ks) {
    #pragma unroll
    for (int j = 0; j < 8; ++j) {
      int c = ks * 32 + g * 8 + j;
      float v = x[((size_t)(b * C_ + c) << 12) + n0 + r];
      ((unsigned short*)&xf[ks])[j] = f2bf(v);
    }
  }
  floatx4 zero = {0.f, 0.f, 0.f, 0.f};

  // ---- V tiles (8 per half) ----
  #pragma unroll 2
  for (int ot = half * 8; ot < half * 8 + 8; ++ot) {
    floatx4 acc = zero;
    #pragma unroll
    for (int ks = 0; ks < 8; ++ks) {
      short8 af = *(const short8*)&wvb[(ot * 16 + r) * 256 + ks * 32 + g * 8];
      acc = __builtin_amdgcn_mfma_f32_16x16x32_bf16(af, xf[ks], acc, 0, 0, 0);
    }
    #pragma unroll
    for (int rr = 0; rr < 4; ++rr) {
      int oc = ot * 16 + g * 4 + rr;
      vbf[((size_t)(b * C_ + oc) << 12) + n0 + r] = f2bf(acc[rr] + bv[oc]);
    }
  }
  // ---- Q (half 0) or K (half 1), 2 tiles ----
  const unsigned short* wb = half ? wkb : wqb;
  const float* bias = half ? bk : bq;
  unsigned short* dst = half ? kbf : qbf;
  int sbase = half ? 256 : 0;
  #pragma unroll 2
  for (int ot = 0; ot < 2; ++ot) {
    floatx4 acc = zero;
    #pragma unroll
    for (int ks = 0; ks < 8; ++ks) {
      short8 af = *(const short8*)&wb[(ot * 16 + r) * 256 + ks * 32 + g * 8];
      acc = __builtin_amdgcn_mfma_f32_16x16x32_bf16(af, xf[ks], acc, 0, 0, 0);
    }
    #pragma unroll
    for (int rr = 0; rr < 4; ++rr) {
      int oc = ot * 16 + g * 4 + rr;
      float val = acc[rr] + bias[oc];
      dst[(size_t)(b * N_ + n0 + r) * 32 + oc] = f2bf(val);
      float s = val * val;               // reduce over the 16 n (lanes r)
      s += __shfl_xor(s, 1);
      s += __shfl_xor(s, 2);
      s += __shfl_xor(s, 4);
      s += __shfl_xor(s, 8);
      if (r == 0) atomicAdd(&ssq[sbase + b * 32 + oc], s);
    }
  }
}

// ---------------- kernel 2: in-place scale of Q,K ----------------
// Q additionally scaled by log2(e) so attention can use raw v_exp_f32 (exp2).
__global__ void scale_kernel(unsigned int* __restrict__ qw, unsigned int* __restrict__ kw,
                             const float* __restrict__ ssq, const float* __restrict__ temp) {
  int tt = blockIdx.x * 256 + threadIdx.x;   // 1,048,576 u32 total (q then k)
  int is_k = tt >> 19;
  int idx = tt & 0x7FFFF;
  unsigned int* ptr = is_k ? kw : qw;
  unsigned int v = ptr[idx];
  int c0 = (idx & 15) * 2;
  int b = idx >> 16;
  float invt = is_k ? 1.0f : LOG2E / (temp[0] + 1e-6f);
  float s0 = ssq[is_k * 256 + b * 32 + c0];
  float s1 = ssq[is_k * 256 + b * 32 + c0 + 1];
  float sc0 = invt / fmaxf(sqrtf(s0), 1e-12f);
  float sc1 = invt / fmaxf(sqrtf(s1), 1e-12f);
  unsigned short lo = f2bf(bf2f((unsigned short)(v & 0xFFFFu)) * sc0);
  unsigned short hi = f2bf(bf2f((unsigned short)(v >> 16)) * sc1);
  ptr[idx] = ((unsigned int)hi << 16) | lo;
}

// ---------------- kernel 3: one-pass attention, m-split x2 ----------------
// S' = S*log2e in [-log2e, 2*log2e]; P = exp2(S' - 2*log2e). No max tracking.
// Block: 32 query rows (2 m-tiles), full n-range. wave w = (mt=w&1, nh=w>>1):
// QK^T for m-tile mt over n-half nh; PV cv-slice w*64. Grid 1024 -> 4 blocks/CU.
// launch_bounds min-waves=2 (NOT 4): VGPR demand ~115; forcing 4 spilled (r3: 547MB scratch).
__launch_bounds__(256, 2)
__global__ void attn_kernel(const unsigned short* __restrict__ qbf,
                            const unsigned short* __restrict__ kbf,
                            const unsigned short* __restrict__ vbf,
                            const float* __restrict__ x, const float* __restrict__ gamma,
                            float* __restrict__ out) {
  __shared__ unsigned short Plds[2][2][16][72];   // [buf][m-tile][m][n(64) pad 72]
  __shared__ float Lbc[2][2][16];                 // [nh][mt][r]
  int b = blockIdx.x & 7, mblk = blockIdx.x >> 3; // mblk in [0,128)
  int w = threadIdx.x >> 6, lane = threadIdx.x & 63;
  int r = lane & 15, g = lane >> 4;
  int mt = w & 1, nh = w >> 1;
  const unsigned short* qb = qbf + (size_t)b * N_ * 32;
  const unsigned short* kb = kbf + (size_t)b * N_ * 32;
  const unsigned short* vb = vbf + (size_t)b * C_ * N_;
  int m0 = mblk * 32 + mt * 16;
  int cvbase = w * 64;
  short8 qfrag = *(const short8*)&qb[(m0 + r) * 32 + g * 8];
  floatx4 zero = {0.f, 0.f, 0.f, 0.f};

  floatx4 acc[2][4];                              // [mt][ct] O^T accum (unnormalized)
  #pragma unroll
  for (int mtt = 0; mtt < 2; ++mtt)
    #pragma unroll
    for (int ct = 0; ct < 4; ++ct) acc[mtt][ct] = zero;
  float Lp = 0.0f;
  int diagnt = mblk >> 1;                         // n-tile containing this block's m rows
  int diagnh = mblk & 1;

  // preload K,V fragments for nt=0
  short8 kf[2], vfA[2][4], vfB[2][4];
  #pragma unroll
  for (int f = 0; f < 2; ++f)
    kf[f] = *(const short8*)&kb[(size_t)(nh * 32 + f * 16 + r) * 32 + g * 8];
  #pragma unroll
  for (int ks = 0; ks < 2; ++ks)
    #pragma unroll
    for (int ct = 0; ct < 4; ++ct)
      vfA[ks][ct] = *(const short8*)&vb[(size_t)(cvbase + ct * 16 + r) * N_ + ks * 32 + g * 8];

  auto body = [&](int nt, short8 (&vcur)[2][4], short8 (&vnxt)[2][4]) {
    int pb = nt & 1;
    int nb2 = ((nt + 1) & 63) * 64;               // wrap: last iter reloads tile 0 (unused)
    floatx4 s[2];
    #pragma unroll
    for (int f = 0; f < 2; ++f)
      s[f] = __builtin_amdgcn_mfma_f32_16x16x32_bf16(kf[f], qfrag, zero, 0, 0, 0);
    // K prefetch for nt+1 (kf dead after the MFMAs above)
    #pragma unroll
    for (int f = 0; f < 2; ++f)
      kf[f] = *(const short8*)&kb[(size_t)(nb2 + nh * 32 + f * 16 + r) * 32 + g * 8];
    // V prefetch for nt+1 — issued EARLY so L2 latency hides under exp/pack
    #pragma unroll
    for (int ks = 0; ks < 2; ++ks)
      #pragma unroll
      for (int ct = 0; ct < 4; ++ct)
        vnxt[ks][ct] = *(const short8*)&vb[(size_t)(cvbase + ct * 16 + r) * N_ + nb2 + ks * 32 + g * 8];
    if (nt == diagnt && nh == diagnh) {           // +I on the diagonal (log2e scale)
      int d = r - 4 * g;
      if (d >= 0 && d < 4) s[mt][d] += LOG2E;
    }
    // P = exp2(S'-2log2e), accumulate L, truncate-pack bf16 -> LDS
    #pragma unroll
    for (int f = 0; f < 2; ++f) {
      float p0 = __builtin_amdgcn_exp2f(s[f][0] - 2.0f * LOG2E);
      float p1 = __builtin_amdgcn_exp2f(s[f][1] - 2.0f * LOG2E);
      float p2 = __builtin_amdgcn_exp2f(s[f][2] - 2.0f * LOG2E);
      float p3 = __builtin_amdgcn_exp2f(s[f][3] - 2.0f * LOG2E);
      Lp += (p0 + p1) + (p2 + p3);
      uint2 uu;
      uu.x = (__float_as_uint(p1) & 0xFFFF0000u) | (__float_as_uint(p0) >> 16);
      uu.y = (__float_as_uint(p3) & 0xFFFF0000u) | (__float_as_uint(p2) >> 16);
      *(uint2*)&Plds[pb][mt][r][nh * 32 + f * 16 + 4 * g] = uu;
    }
    __syncthreads();                              // P[pb] visible to all waves
    #pragma unroll
    for (int ks = 0; ks < 2; ++ks) {
      short8 pf[2];
      #pragma unroll
      for (int mtt = 0; mtt < 2; ++mtt)
        pf[mtt] = *(const short8*)&Plds[pb][mtt][r][ks * 32 + g * 8];
      #pragma unroll
      for (int ct = 0; ct < 4; ++ct)
        #pragma unroll
        for (int mtt = 0; mtt < 2; ++mtt)
          acc[mtt][ct] = __builtin_amdgcn_mfma_f32_16x16x32_bf16(vcur[ks][ct], pf[mtt], acc[mtt][ct], 0, 0, 0);
    }
  };
  #pragma unroll 1
  for (int nt = 0; nt < 64; nt += 2) { body(nt, vfA, vfB); body(nt + 1, vfB, vfA); }

  // column denominators: g-reduce in-wave, combine the two nh halves via LDS
  Lp += __shfl_xor(Lp, 16);
  Lp += __shfl_xor(Lp, 32);
  if (lane < 16) Lbc[nh][mt][lane] = Lp;
  __syncthreads();
  float linv[2];
  #pragma unroll
  for (int mtt = 0; mtt < 2; ++mtt)
    linv[mtt] = 1.0f / (Lbc[0][mtt][r] + Lbc[1][mtt][r]);

  // epilogue: out = gamma * (O/L) + x
  float gam = gamma[0];
  #pragma unroll
  for (int mtt = 0; mtt < 2; ++mtt)
    #pragma unroll
    for (int ct = 0; ct < 4; ++ct)
      #pragma unroll
      for (int rr = 0; rr < 4; ++rr) {
        int cv = cvbase + ct * 16 + g * 4 + rr;
        int m = mblk * 32 + mtt * 16 + r;
        size_t idx = ((size_t)(b * C_ + cv) << 12) + m;
        out[idx] = gam * acc[mtt][ct][rr] * linv[mtt] + x[idx];
      }
}

extern "C" void kernel_launch(void* const* d_in, const int* in_sizes, int n_in,
                              void* d_out, int out_size, void* d_ws, size_t ws_size,
                              hipStream_t stream) {
  (void)in_sizes; (void)n_in; (void)out_size; (void)ws_size;
  const float* x    = (const float*)d_in[0];
  const float* Wq   = (const float*)d_in[1];
  const float* bq   = (const float*)d_in[2];
  const float* Wk   = (const float*)d_in[3];
  const float* bk   = (const float*)d_in[4];
  const float* Wv   = (const float*)d_in[5];
  const float* bv   = (const float*)d_in[6];
  const float* gam  = (const float*)d_in[7];
  const float* temp = (const float*)d_in[8];
  float* out = (float*)d_out;

  char* ws = (char*)d_ws;
  unsigned short* vbf = (unsigned short*)ws;                       // 16 MB
  unsigned short* qbf = (unsigned short*)(ws + (16u << 20));       // 2 MB
  unsigned short* kbf = (unsigned short*)(ws + (18u << 20));       // 2 MB
  unsigned short* wqb = (unsigned short*)(ws + (20u << 20));       // 16 KB
  unsigned short* wkb = wqb + 8192;                                // 16 KB
  unsigned short* wvb = wkb + 8192;                                // 128 KB
  float* ssq = (float*)(wvb + 65536);                              // 2 KB

  prep_kernel<<<dim3(288), dim3(256), 0, stream>>>(Wq, Wk, Wv, wqb, wkb, wvb, ssq);
  qkv_kernel<<<dim3(1024), dim3(256), 0, stream>>>(x, wqb, wkb, wvb, bq, bk, bv, qbf, kbf, vbf, ssq);
  scale_kernel<<<dim3(4096), dim3(256), 0, stream>>>((unsigned int*)qbf, (unsigned int*)kbf, ssq, temp);
  attn_kernel<<<dim3(1024), dim3(256), 0, stream>>>(qbf, kbf, vbf, x, gam, out);
}

// Round 5
// 252.623 us; speedup vs baseline: 2.1210x; 1.4027x over previous
//
#include <hip/hip_runtime.h>
#include <hip/hip_bf16.h>
#include <math.h>

typedef __attribute__((ext_vector_type(8))) short short8;
typedef __attribute__((ext_vector_type(4))) float floatx4;

#define B_ 8
#define C_ 256
#define N_ 4096
#define LOG2E 1.4426950408889634f

static __device__ __forceinline__ unsigned short f2bf(float f) {
  union { float f; unsigned int u; } v; v.f = f;
  unsigned int u = v.u;
  u += 0x7FFFu + ((u >> 16) & 1u);   // RNE
  return (unsigned short)(u >> 16);
}
static __device__ __forceinline__ float bf2f(unsigned short h) {
  union { unsigned int u; float f; } v; v.u = ((unsigned int)h) << 16; return v.f;
}

// ---------------- kernel 0: weight convert + ssq zero ----------------
__global__ void prep_kernel(const float* __restrict__ Wq, const float* __restrict__ Wk,
                            const float* __restrict__ Wv,
                            unsigned short* __restrict__ wqb, unsigned short* __restrict__ wkb,
                            unsigned short* __restrict__ wvb, float* __restrict__ ssq) {
  int t = blockIdx.x * 256 + threadIdx.x;
  if (t < 512) ssq[t] = 0.0f;
  if (t < 8192) { wqb[t] = f2bf(Wq[t]); wkb[t] = f2bf(Wk[t]); }
  int tv = t - 8192;
  if (tv >= 0 && tv < 65536) wvb[tv] = f2bf(Wv[tv]);
}

// ---------------- kernel 1: QKV GEMM, channel-split x2 ----------------
// half 0: V channels 0..127 + Q ; half 1: V channels 128..255 + K
__launch_bounds__(256, 4)
__global__ void qkv_kernel(const float* __restrict__ x,
                           const unsigned short* __restrict__ wqb,
                           const unsigned short* __restrict__ wkb,
                           const unsigned short* __restrict__ wvb,
                           const float* __restrict__ bq, const float* __restrict__ bk,
                           const float* __restrict__ bv,
                           unsigned short* __restrict__ qbf, unsigned short* __restrict__ kbf,
                           unsigned short* __restrict__ vbf, float* __restrict__ ssq) {
  int b = blockIdx.x & 7;
  int nblk = (blockIdx.x >> 3) & 63;
  int half = blockIdx.x >> 9;
  int w = threadIdx.x >> 6, lane = threadIdx.x & 63;
  int r = lane & 15, g = lane >> 4;
  int n0 = nblk * 64 + w * 16;

  // B fragments from x: B[k=c][col=n], lane: col=r, k = g*8+j (per 32-k step)
  short8 xf[8];
  #pragma unroll
  for (int ks = 0; ks < 8; ++ks) {
    #pragma unroll
    for (int j = 0; j < 8; ++j) {
      int c = ks * 32 + g * 8 + j;
      float v = x[((size_t)(b * C_ + c) << 12) + n0 + r];
      ((unsigned short*)&xf[ks])[j] = f2bf(v);
    }
  }
  floatx4 zero = {0.f, 0.f, 0.f, 0.f};

  // ---- V tiles (8 per half) ----
  #pragma unroll 2
  for (int ot = half * 8; ot < half * 8 + 8; ++ot) {
    floatx4 acc = zero;
    #pragma unroll
    for (int ks = 0; ks < 8; ++ks) {
      short8 af = *(const short8*)&wvb[(ot * 16 + r) * 256 + ks * 32 + g * 8];
      acc = __builtin_amdgcn_mfma_f32_16x16x32_bf16(af, xf[ks], acc, 0, 0, 0);
    }
    #pragma unroll
    for (int rr = 0; rr < 4; ++rr) {
      int oc = ot * 16 + g * 4 + rr;
      vbf[((size_t)(b * C_ + oc) << 12) + n0 + r] = f2bf(acc[rr] + bv[oc]);
    }
  }
  // ---- Q (half 0) or K (half 1), 2 tiles ----
  const unsigned short* wb = half ? wkb : wqb;
  const float* bias = half ? bk : bq;
  unsigned short* dst = half ? kbf : qbf;
  int sbase = half ? 256 : 0;
  #pragma unroll 2
  for (int ot = 0; ot < 2; ++ot) {
    floatx4 acc = zero;
    #pragma unroll
    for (int ks = 0; ks < 8; ++ks) {
      short8 af = *(const short8*)&wb[(ot * 16 + r) * 256 + ks * 32 + g * 8];
      acc = __builtin_amdgcn_mfma_f32_16x16x32_bf16(af, xf[ks], acc, 0, 0, 0);
    }
    #pragma unroll
    for (int rr = 0; rr < 4; ++rr) {
      int oc = ot * 16 + g * 4 + rr;
      float val = acc[rr] + bias[oc];
      dst[(size_t)(b * N_ + n0 + r) * 32 + oc] = f2bf(val);
      float s = val * val;               // reduce over the 16 n (lanes r)
      s += __shfl_xor(s, 1);
      s += __shfl_xor(s, 2);
      s += __shfl_xor(s, 4);
      s += __shfl_xor(s, 8);
      if (r == 0) atomicAdd(&ssq[sbase + b * 32 + oc], s);
    }
  }
}

// ---------------- kernel 2: in-place scale of Q,K ----------------
// Q additionally scaled by log2(e) so attention can use raw v_exp_f32 (exp2).
__global__ void scale_kernel(unsigned int* __restrict__ qw, unsigned int* __restrict__ kw,
                             const float* __restrict__ ssq, const float* __restrict__ temp) {
  int tt = blockIdx.x * 256 + threadIdx.x;   // 1,048,576 u32 total (q then k)
  int is_k = tt >> 19;
  int idx = tt & 0x7FFFF;
  unsigned int* ptr = is_k ? kw : qw;
  unsigned int v = ptr[idx];
  int c0 = (idx & 15) * 2;
  int b = idx >> 16;
  float invt = is_k ? 1.0f : LOG2E / (temp[0] + 1e-6f);
  float s0 = ssq[is_k * 256 + b * 32 + c0];
  float s1 = ssq[is_k * 256 + b * 32 + c0 + 1];
  float sc0 = invt / fmaxf(sqrtf(s0), 1e-12f);
  float sc1 = invt / fmaxf(sqrtf(s1), 1e-12f);
  unsigned short lo = f2bf(bf2f((unsigned short)(v & 0xFFFFu)) * sc0);
  unsigned short hi = f2bf(bf2f((unsigned short)(v >> 16)) * sc1);
  ptr[idx] = ((unsigned int)hi << 16) | lo;
}

// ---------------- kernel 3: pipelined one-pass attention ----------------
// Round-2 structure (64 m rows, 4 waves, grid 512) + software pipeline:
// per tile: [issue K(t+1),V(t+1)] -> PV(t) -> QK(t+1) -> exp/pack -> barrier.
// Loads are issued ~one full phase before the barrier that drains them -> no
// exposed latency. Hoisted per-lane pointers (imm offsets) kill addr VALU.
// Plds row stride 88 elems (176B): 16B-aligned b128 reads, 2-way banks (free).
__launch_bounds__(256, 2)
__global__ void attn_kernel(const unsigned short* __restrict__ qbf,
                            const unsigned short* __restrict__ kbf,
                            const unsigned short* __restrict__ vbf,
                            const float* __restrict__ x, const float* __restrict__ gamma,
                            float* __restrict__ out) {
  __shared__ unsigned short Plds[2][4][16][88];   // [buf][m-tile][m][n(64) pad 88]
  __shared__ float Lbc[64];
  int b = blockIdx.x & 7, mblk = blockIdx.x >> 3; // mblk in [0,64)
  int w = threadIdx.x >> 6, lane = threadIdx.x & 63;
  int r = lane & 15, g = lane >> 4;
  const unsigned short* qb = qbf + (size_t)b * N_ * 32;
  const unsigned short* kb = kbf + (size_t)b * N_ * 32;
  const unsigned short* vb = vbf + (size_t)b * C_ * N_;
  int m0 = mblk * 64 + w * 16;
  int cvbase = w * 64;
  short8 qfrag = *(const short8*)&qb[(m0 + r) * 32 + g * 8];
  floatx4 zero = {0.f, 0.f, 0.f, 0.f};

  floatx4 acc[4][4];                              // [mt][ct] O^T accum (unnormalized)
  #pragma unroll
  for (int mt = 0; mt < 4; ++mt)
    #pragma unroll
    for (int ct = 0; ct < 4; ++ct) acc[mt][ct] = zero;
  float Lp = 0.0f;

  // hoisted per-lane pointers: K advances 4096B/tile, V advances 128B/tile
  const unsigned short* kp = kb + r * 32 + g * 8;           // + f*512 imm
  const unsigned short* vp0 = vb + (size_t)(cvbase +  0 + r) * N_ + g * 8;  // + ks*32 imm
  const unsigned short* vp1 = vb + (size_t)(cvbase + 16 + r) * N_ + g * 8;
  const unsigned short* vp2 = vb + (size_t)(cvbase + 32 + r) * N_ + g * 8;
  const unsigned short* vp3 = vb + (size_t)(cvbase + 48 + r) * N_ + g * 8;

  short8 kf[4], vfA[2][4], vfB[2][4];

  // exp/pack of tile tt into Plds[tt&1] from s[4]
  auto dopack = [&](int tt, floatx4 (&s)[4]) {
    if (tt == mblk) {                             // +I on the diagonal (log2e scale)
      int d = r - 4 * g;
      if (d >= 0 && d < 4) s[w][d] += LOG2E;
    }
    int pb = tt & 1;
    #pragma unroll
    for (int f = 0; f < 4; ++f) {
      float p0 = __builtin_amdgcn_exp2f(s[f][0] - 2.0f * LOG2E);
      float p1 = __builtin_amdgcn_exp2f(s[f][1] - 2.0f * LOG2E);
      float p2 = __builtin_amdgcn_exp2f(s[f][2] - 2.0f * LOG2E);
      float p3 = __builtin_amdgcn_exp2f(s[f][3] - 2.0f * LOG2E);
      Lp += (p0 + p1) + (p2 + p3);
      uint2 uu;
      uu.x = (__float_as_uint(p1) & 0xFFFF0000u) | (__float_as_uint(p0) >> 16);
      uu.y = (__float_as_uint(p3) & 0xFFFF0000u) | (__float_as_uint(p2) >> 16);
      *(uint2*)&Plds[pb][w][r][f * 16 + 4 * g] = uu;
    }
  };

  // ---- prologue: QK(0), pack P(0), load V(0), K(1) positioned ----
  {
    #pragma unroll
    for (int f = 0; f < 4; ++f) kf[f] = *(const short8*)(kp + f * 512);
    kp += 2048;
    floatx4 s[4];
    #pragma unroll
    for (int f = 0; f < 4; ++f)
      s[f] = __builtin_amdgcn_mfma_f32_16x16x32_bf16(kf[f], qfrag, zero, 0, 0, 0);
    dopack(0, s);
    #pragma unroll
    for (int ks = 0; ks < 2; ++ks) {
      vfA[ks][0] = *(const short8*)(vp0 + ks * 32);
      vfA[ks][1] = *(const short8*)(vp1 + ks * 32);
      vfA[ks][2] = *(const short8*)(vp2 + ks * 32);
      vfA[ks][3] = *(const short8*)(vp3 + ks * 32);
    }
    vp0 += 64; vp1 += 64; vp2 += 64; vp3 += 64;
    __syncthreads();
  }

  auto body = [&](int t, short8 (&vcur)[2][4], short8 (&vnxt)[2][4]) {
    int t1 = t + 1;
    if (t1 < 64) {
      // issue K(t+1) and V(t+1) loads — consumed after PV / next body
      #pragma unroll
      for (int f = 0; f < 4; ++f) kf[f] = *(const short8*)(kp + f * 512);
      kp += 2048;
      #pragma unroll
      for (int ks = 0; ks < 2; ++ks) {
        vnxt[ks][0] = *(const short8*)(vp0 + ks * 32);
        vnxt[ks][1] = *(const short8*)(vp1 + ks * 32);
        vnxt[ks][2] = *(const short8*)(vp2 + ks * 32);
        vnxt[ks][3] = *(const short8*)(vp3 + ks * 32);
      }
      vp0 += 64; vp1 += 64; vp2 += 64; vp3 += 64;
    }
    // PV(t): P from Plds[t&1], V from regs
    int pb = t & 1;
    #pragma unroll
    for (int ks = 0; ks < 2; ++ks) {
      short8 pf[4];
      #pragma unroll
      for (int mt = 0; mt < 4; ++mt)
        pf[mt] = *(const short8*)&Plds[pb][mt][r][ks * 32 + g * 8];
      #pragma unroll
      for (int ct = 0; ct < 4; ++ct)
        #pragma unroll
        for (int mt = 0; mt < 4; ++mt)
          acc[mt][ct] = __builtin_amdgcn_mfma_f32_16x16x32_bf16(vcur[ks][ct], pf[mt], acc[mt][ct], 0, 0, 0);
    }
    // QK(t+1) + pack into Plds[(t+1)&1]
    if (t1 < 64) {
      floatx4 s[4];
      #pragma unroll
      for (int f = 0; f < 4; ++f)
        s[f] = __builtin_amdgcn_mfma_f32_16x16x32_bf16(kf[f], qfrag, zero, 0, 0, 0);
      dopack(t1, s);
    }
    __syncthreads();
  };

  #pragma unroll 1
  for (int t = 0; t < 64; t += 2) { body(t, vfA, vfB); body(t + 1, vfB, vfA); }

  // column denominators: combine the 4 g-partials, broadcast via LDS
  Lp += __shfl_xor(Lp, 16);
  Lp += __shfl_xor(Lp, 32);
  if (g == 0) Lbc[w * 16 + r] = Lp;
  __syncthreads();
  float linv[4];
  #pragma unroll
  for (int mt = 0; mt < 4; ++mt) linv[mt] = 1.0f / Lbc[mt * 16 + r];

  // epilogue: out = gamma * (O/L) + x
  float gam = gamma[0];
  #pragma unroll
  for (int mt = 0; mt < 4; ++mt)
    #pragma unroll
    for (int ct = 0; ct < 4; ++ct)
      #pragma unroll
      for (int rr = 0; rr < 4; ++rr) {
        int cv = cvbase + ct * 16 + g * 4 + rr;
        int m = mblk * 64 + mt * 16 + r;
        size_t idx = ((size_t)(b * C_ + cv) << 12) + m;
        out[idx] = gam * acc[mt][ct][rr] * linv[mt] + x[idx];
      }
}

extern "C" void kernel_launch(void* const* d_in, const int* in_sizes, int n_in,
                              void* d_out, int out_size, void* d_ws, size_t ws_size,
                              hipStream_t stream) {
  (void)in_sizes; (void)n_in; (void)out_size; (void)ws_size;
  const float* x    = (const float*)d_in[0];
  const float* Wq   = (const float*)d_in[1];
  const float* bq   = (const float*)d_in[2];
  const float* Wk   = (const float*)d_in[3];
  const float* bk   = (const float*)d_in[4];
  const float* Wv   = (const float*)d_in[5];
  const float* bv   = (const float*)d_in[6];
  const float* gam  = (const float*)d_in[7];
  const float* temp = (const float*)d_in[8];
  float* out = (float*)d_out;

  char* ws = (char*)d_ws;
  unsigned short* vbf = (unsigned short*)ws;                       // 16 MB
  unsigned short* qbf = (unsigned short*)(ws + (16u << 20));       // 2 MB
  unsigned short* kbf = (unsigned short*)(ws + (18u << 20));       // 2 MB
  unsigned short* wqb = (unsigned short*)(ws + (20u << 20));       // 16 KB
  unsigned short* wkb = wqb + 8192;                                // 16 KB
  unsigned short* wvb = wkb + 8192;                                // 128 KB
  float* ssq = (float*)(wvb + 65536);                              // 2 KB

  prep_kernel<<<dim3(288), dim3(256), 0, stream>>>(Wq, Wk, Wv, wqb, wkb, wvb, ssq);
  qkv_kernel<<<dim3(1024), dim3(256), 0, stream>>>(x, wqb, wkb, wvb, bq, bk, bv, qbf, kbf, vbf, ssq);
  scale_kernel<<<dim3(4096), dim3(256), 0, stream>>>((unsigned int*)qbf, (unsigned int*)kbf, ssq, temp);
  attn_kernel<<<dim3(512), dim3(256), 0, stream>>>(qbf, kbf, vbf, x, gam, out);
}

// Round 6
// 247.220 us; speedup vs baseline: 2.1674x; 1.0219x over previous
//
#include <hip/hip_runtime.h>
#include <hip/hip_bf16.h>
#include <math.h>

typedef __attribute__((ext_vector_type(8))) short short8;
typedef __attribute__((ext_vector_type(4))) float floatx4;

#define B_ 8
#define C_ 256
#define N_ 4096
#define LOG2E 1.4426950408889634f

static __device__ __forceinline__ unsigned short f2bf(float f) {
  union { float f; unsigned int u; } v; v.f = f;
  unsigned int u = v.u;
  u += 0x7FFFu + ((u >> 16) & 1u);   // RNE
  return (unsigned short)(u >> 16);
}
static __device__ __forceinline__ float bf2f(unsigned short h) {
  union { unsigned int u; float f; } v; v.u = ((unsigned int)h) << 16; return v.f;
}

// ---------------- kernel 0: weight convert + ssq zero ----------------
__global__ void prep_kernel(const float* __restrict__ Wq, const float* __restrict__ Wk,
                            const float* __restrict__ Wv,
                            unsigned short* __restrict__ wqb, unsigned short* __restrict__ wkb,
                            unsigned short* __restrict__ wvb, float* __restrict__ ssq) {
  int t = blockIdx.x * 256 + threadIdx.x;
  if (t < 512) ssq[t] = 0.0f;
  if (t < 8192) { wqb[t] = f2bf(Wq[t]); wkb[t] = f2bf(Wk[t]); }
  int tv = t - 8192;
  if (tv >= 0 && tv < 65536) wvb[tv] = f2bf(Wv[tv]);
}

// ---------------- kernel 1: QKV GEMM, channel-split x2 ----------------
// half 0: V channels 0..127 + Q ; half 1: V channels 128..255 + K
__launch_bounds__(256, 4)
__global__ void qkv_kernel(const float* __restrict__ x,
                           const unsigned short* __restrict__ wqb,
                           const unsigned short* __restrict__ wkb,
                           const unsigned short* __restrict__ wvb,
                           const float* __restrict__ bq, const float* __restrict__ bk,
                           const float* __restrict__ bv,
                           unsigned short* __restrict__ qbf, unsigned short* __restrict__ kbf,
                           unsigned short* __restrict__ vbf, float* __restrict__ ssq) {
  int b = blockIdx.x & 7;
  int nblk = (blockIdx.x >> 3) & 63;
  int half = blockIdx.x >> 9;
  int w = threadIdx.x >> 6, lane = threadIdx.x & 63;
  int r = lane & 15, g = lane >> 4;
  int n0 = nblk * 64 + w * 16;

  // B fragments from x: B[k=c][col=n], lane: col=r, k = g*8+j (per 32-k step)
  short8 xf[8];
  #pragma unroll
  for (int ks = 0; ks < 8; ++ks) {
    #pragma unroll
    for (int j = 0; j < 8; ++j) {
      int c = ks * 32 + g * 8 + j;
      float v = x[((size_t)(b * C_ + c) << 12) + n0 + r];
      ((unsigned short*)&xf[ks])[j] = f2bf(v);
    }
  }
  floatx4 zero = {0.f, 0.f, 0.f, 0.f};

  // ---- V tiles (8 per half) ----
  #pragma unroll 2
  for (int ot = half * 8; ot < half * 8 + 8; ++ot) {
    floatx4 acc = zero;
    #pragma unroll
    for (int ks = 0; ks < 8; ++ks) {
      short8 af = *(const short8*)&wvb[(ot * 16 + r) * 256 + ks * 32 + g * 8];
      acc = __builtin_amdgcn_mfma_f32_16x16x32_bf16(af, xf[ks], acc, 0, 0, 0);
    }
    #pragma unroll
    for (int rr = 0; rr < 4; ++rr) {
      int oc = ot * 16 + g * 4 + rr;
      vbf[((size_t)(b * C_ + oc) << 12) + n0 + r] = f2bf(acc[rr] + bv[oc]);
    }
  }
  // ---- Q (half 0) or K (half 1), 2 tiles ----
  const unsigned short* wb = half ? wkb : wqb;
  const float* bias = half ? bk : bq;
  unsigned short* dst = half ? kbf : qbf;
  int sbase = half ? 256 : 0;
  #pragma unroll 2
  for (int ot = 0; ot < 2; ++ot) {
    floatx4 acc = zero;
    #pragma unroll
    for (int ks = 0; ks < 8; ++ks) {
      short8 af = *(const short8*)&wb[(ot * 16 + r) * 256 + ks * 32 + g * 8];
      acc = __builtin_amdgcn_mfma_f32_16x16x32_bf16(af, xf[ks], acc, 0, 0, 0);
    }
    #pragma unroll
    for (int rr = 0; rr < 4; ++rr) {
      int oc = ot * 16 + g * 4 + rr;
      float val = acc[rr] + bias[oc];
      dst[(size_t)(b * N_ + n0 + r) * 32 + oc] = f2bf(val);
      float s = val * val;               // reduce over the 16 n (lanes r)
      s += __shfl_xor(s, 1);
      s += __shfl_xor(s, 2);
      s += __shfl_xor(s, 4);
      s += __shfl_xor(s, 8);
      if (r == 0) atomicAdd(&ssq[sbase + b * 32 + oc], s);
    }
  }
}

// ---------------- kernel 2: in-place scale of Q,K ----------------
// Q additionally scaled by log2(e) so attention can use raw v_exp_f32 (exp2).
__global__ void scale_kernel(unsigned int* __restrict__ qw, unsigned int* __restrict__ kw,
                             const float* __restrict__ ssq, const float* __restrict__ temp) {
  int tt = blockIdx.x * 256 + threadIdx.x;   // 1,048,576 u32 total (q then k)
  int is_k = tt >> 19;
  int idx = tt & 0x7FFFF;
  unsigned int* ptr = is_k ? kw : qw;
  unsigned int v = ptr[idx];
  int c0 = (idx & 15) * 2;
  int b = idx >> 16;
  float invt = is_k ? 1.0f : LOG2E / (temp[0] + 1e-6f);
  float s0 = ssq[is_k * 256 + b * 32 + c0];
  float s1 = ssq[is_k * 256 + b * 32 + c0 + 1];
  float sc0 = invt / fmaxf(sqrtf(s0), 1e-12f);
  float sc1 = invt / fmaxf(sqrtf(s1), 1e-12f);
  unsigned short lo = f2bf(bf2f((unsigned short)(v & 0xFFFFu)) * sc0);
  unsigned short hi = f2bf(bf2f((unsigned short)(v >> 16)) * sc1);
  ptr[idx] = ((unsigned int)hi << 16) | lo;
}

// ---------------- kernel 3: pipelined one-pass attention, 8 waves ----------------
// 64 m rows/block, 512 threads (8 waves), grid 512 -> 2 blocks/CU = 16 waves/CU.
// Wave w: (mt = w&3, nh = w>>2). QK^T: m-tile mt over n-half nh of each 64-tile
// (2 MFMA). PV: cv-slice [w*32, w*32+32) (16 MFMA). Same per-block V/K traffic
// as the 4-wave version, 2x the wave concurrency per SIMD.
// Per tile: [issue K(t+1),V(t+1)] -> PV(t) -> QK(t+1) -> exp/pack -> barrier.
__launch_bounds__(512, 4)
__global__ void attn_kernel(const unsigned short* __restrict__ qbf,
                            const unsigned short* __restrict__ kbf,
                            const unsigned short* __restrict__ vbf,
                            const float* __restrict__ x, const float* __restrict__ gamma,
                            float* __restrict__ out) {
  __shared__ unsigned short Plds[2][4][16][88];   // [buf][m-tile][m][n(64) pad 88]
  __shared__ float Lbc[8][16];
  int b = blockIdx.x & 7, mblk = blockIdx.x >> 3; // mblk in [0,64)
  int w = threadIdx.x >> 6, lane = threadIdx.x & 63;
  int r = lane & 15, g = lane >> 4;
  int mt = w & 3, nh = w >> 2;
  const unsigned short* qb = qbf + (size_t)b * N_ * 32;
  const unsigned short* kb = kbf + (size_t)b * N_ * 32;
  const unsigned short* vb = vbf + (size_t)b * C_ * N_;
  short8 qfrag = *(const short8*)&qb[(mblk * 64 + mt * 16 + r) * 32 + g * 8];
  floatx4 zero = {0.f, 0.f, 0.f, 0.f};

  floatx4 acc[4][2];                              // [m-tile][ct] O^T accum
  #pragma unroll
  for (int mtt = 0; mtt < 4; ++mtt)
    #pragma unroll
    for (int ct = 0; ct < 2; ++ct) acc[mtt][ct] = zero;
  float Lp = 0.0f;

  // hoisted per-lane pointers: K advances 4096B/tile, V advances 128B/tile
  const unsigned short* kp = kb + (size_t)(nh * 32 + r) * 32 + g * 8;        // + f*512 imm
  const unsigned short* vp0 = vb + (size_t)(w * 32 + r) * N_ + g * 8;        // + ks*32 imm
  const unsigned short* vp1 = vb + (size_t)(w * 32 + 16 + r) * N_ + g * 8;

  short8 kf[2], vfA[2][2], vfB[2][2];

  // exp/pack of tile tt into Plds[tt&1] from s[2] (this wave's n-half)
  auto dopack = [&](int tt, floatx4 (&s)[2]) {
    if (tt == mblk && nh == (mt >> 1)) {          // +I on the diagonal (log2e scale)
      int d = r - 4 * g;
      if (d >= 0 && d < 4) s[mt & 1][d] += LOG2E;
    }
    int pb = tt & 1;
    #pragma unroll
    for (int f = 0; f < 2; ++f) {
      float p0 = __builtin_amdgcn_exp2f(s[f][0] - 2.0f * LOG2E);
      float p1 = __builtin_amdgcn_exp2f(s[f][1] - 2.0f * LOG2E);
      float p2 = __builtin_amdgcn_exp2f(s[f][2] - 2.0f * LOG2E);
      float p3 = __builtin_amdgcn_exp2f(s[f][3] - 2.0f * LOG2E);
      Lp += (p0 + p1) + (p2 + p3);
      uint2 uu;
      uu.x = (__float_as_uint(p1) & 0xFFFF0000u) | (__float_as_uint(p0) >> 16);
      uu.y = (__float_as_uint(p3) & 0xFFFF0000u) | (__float_as_uint(p2) >> 16);
      *(uint2*)&Plds[pb][mt][r][nh * 32 + f * 16 + 4 * g] = uu;
    }
  };

  // ---- prologue: QK(0), pack P(0), load V(0) ----
  {
    #pragma unroll
    for (int f = 0; f < 2; ++f) kf[f] = *(const short8*)(kp + f * 512);
    kp += 2048;
    floatx4 s[2];
    #pragma unroll
    for (int f = 0; f < 2; ++f)
      s[f] = __builtin_amdgcn_mfma_f32_16x16x32_bf16(kf[f], qfrag, zero, 0, 0, 0);
    dopack(0, s);
    #pragma unroll
    for (int ks = 0; ks < 2; ++ks) {
      vfA[ks][0] = *(const short8*)(vp0 + ks * 32);
      vfA[ks][1] = *(const short8*)(vp1 + ks * 32);
    }
    vp0 += 64; vp1 += 64;
    __syncthreads();
  }

  auto body = [&](int t, short8 (&vcur)[2][2], short8 (&vnxt)[2][2]) {
    int t1 = t + 1;
    if (t1 < 64) {
      // issue K(t+1) and V(t+1) loads — consumed after PV / next body
      #pragma unroll
      for (int f = 0; f < 2; ++f) kf[f] = *(const short8*)(kp + f * 512);
      kp += 2048;
      #pragma unroll
      for (int ks = 0; ks < 2; ++ks) {
        vnxt[ks][0] = *(const short8*)(vp0 + ks * 32);
        vnxt[ks][1] = *(const short8*)(vp1 + ks * 32);
      }
      vp0 += 64; vp1 += 64;
    }
    // PV(t): P from Plds[t&1], V from regs
    int pb = t & 1;
    #pragma unroll
    for (int ks = 0; ks < 2; ++ks) {
      short8 pf[4];
      #pragma unroll
      for (int mtt = 0; mtt < 4; ++mtt)
        pf[mtt] = *(const short8*)&Plds[pb][mtt][r][ks * 32 + g * 8];
      #pragma unroll
      for (int ct = 0; ct < 2; ++ct)
        #pragma unroll
        for (int mtt = 0; mtt < 4; ++mtt)
          acc[mtt][ct] = __builtin_amdgcn_mfma_f32_16x16x32_bf16(vcur[ks][ct], pf[mtt], acc[mtt][ct], 0, 0, 0);
    }
    // QK(t+1) + pack into Plds[(t+1)&1]
    if (t1 < 64) {
      floatx4 s[2];
      #pragma unroll
      for (int f = 0; f < 2; ++f)
        s[f] = __builtin_amdgcn_mfma_f32_16x16x32_bf16(kf[f], qfrag, zero, 0, 0, 0);
      dopack(t1, s);
    }
    __syncthreads();
  };

  #pragma unroll 1
  for (int t = 0; t < 64; t += 2) { body(t, vfA, vfB); body(t + 1, vfB, vfA); }

  // column denominators: combine 4 g-partials in-wave, then the 2 nh halves via LDS
  Lp += __shfl_xor(Lp, 16);
  Lp += __shfl_xor(Lp, 32);
  if (g == 0) Lbc[w][r] = Lp;
  __syncthreads();
  float linv[4];
  #pragma unroll
  for (int mtt = 0; mtt < 4; ++mtt)
    linv[mtt] = 1.0f / (Lbc[mtt][r] + Lbc[mtt + 4][r]);

  // epilogue: out = gamma * (O/L) + x
  float gam = gamma[0];
  #pragma unroll
  for (int mtt = 0; mtt < 4; ++mtt)
    #pragma unroll
    for (int ct = 0; ct < 2; ++ct)
      #pragma unroll
      for (int rr = 0; rr < 4; ++rr) {
        int cv = w * 32 + ct * 16 + g * 4 + rr;
        int m = mblk * 64 + mtt * 16 + r;
        size_t idx = ((size_t)(b * C_ + cv) << 12) + m;
        out[idx] = gam * acc[mtt][ct][rr] * linv[mtt] + x[idx];
      }
}

extern "C" void kernel_launch(void* const* d_in, const int* in_sizes, int n_in,
                              void* d_out, int out_size, void* d_ws, size_t ws_size,
                              hipStream_t stream) {
  (void)in_sizes; (void)n_in; (void)out_size; (void)ws_size;
  const float* x    = (const float*)d_in[0];
  const float* Wq   = (const float*)d_in[1];
  const float* bq   = (const float*)d_in[2];
  const float* Wk   = (const float*)d_in[3];
  const float* bk   = (const float*)d_in[4];
  const float* Wv   = (const float*)d_in[5];
  const float* bv   = (const float*)d_in[6];
  const float* gam  = (const float*)d_in[7];
  const float* temp = (const float*)d_in[8];
  float* out = (float*)d_out;

  char* ws = (char*)d_ws;
  unsigned short* vbf = (unsigned short*)ws;                       // 16 MB
  unsigned short* qbf = (unsigned short*)(ws + (16u << 20));       // 2 MB
  unsigned short* kbf = (unsigned short*)(ws + (18u << 20));       // 2 MB
  unsigned short* wqb = (unsigned short*)(ws + (20u << 20));       // 16 KB
  unsigned short* wkb = wqb + 8192;                                // 16 KB
  unsigned short* wvb = wkb + 8192;                                // 128 KB
  float* ssq = (float*)(wvb + 65536);                              // 2 KB

  prep_kernel<<<dim3(288), dim3(256), 0, stream>>>(Wq, Wk, Wv, wqb, wkb, wvb, ssq);
  qkv_kernel<<<dim3(1024), dim3(256), 0, stream>>>(x, wqb, wkb, wvb, bq, bk, bv, qbf, kbf, vbf, ssq);
  scale_kernel<<<dim3(4096), dim3(256), 0, stream>>>((unsigned int*)qbf, (unsigned int*)kbf, ssq, temp);
  attn_kernel<<<dim3(512), dim3(512), 0, stream>>>(qbf, kbf, vbf, x, gam, out);
}

// Round 8
// 205.685 us; speedup vs baseline: 2.6050x; 1.2019x over previous
//
#include <hip/hip_runtime.h>
#include <hip/hip_bf16.h>
#include <math.h>

typedef __attribute__((ext_vector_type(8))) short short8;
typedef __attribute__((ext_vector_type(4))) float floatx4;
typedef __attribute__((ext_vector_type(16))) float floatx16;

#define B_ 8
#define C_ 256
#define N_ 4096
#define LOG2E 1.4426950408889634f
#define VSTRIDE 80   // bytes per 32-elem LDS row: 64 + 16 pad -> bijective, 16B-aligned, bank-floor

static __device__ __forceinline__ unsigned short f2bf(float f) {
  union { float f; unsigned int u; } v; v.f = f;
  unsigned int u = v.u;
  u += 0x7FFFu + ((u >> 16) & 1u);   // RNE
  return (unsigned short)(u >> 16);
}
static __device__ __forceinline__ float bf2f(unsigned short h) {
  union { unsigned int u; float f; } v; v.u = ((unsigned int)h) << 16; return v.f;
}
// truncation pack of two positive f32 -> packed bf16x2 (lo = a, hi = b)
static __device__ __forceinline__ unsigned int pk2(float a, float b) {
  return (__float_as_uint(b) & 0xFFFF0000u) | (__float_as_uint(a) >> 16);
}

// ---------------- kernel 0: weight convert + ssq zero ----------------
__global__ void prep_kernel(const float* __restrict__ Wq, const float* __restrict__ Wk,
                            const float* __restrict__ Wv,
                            unsigned short* __restrict__ wqb, unsigned short* __restrict__ wkb,
                            unsigned short* __restrict__ wvb, float* __restrict__ ssq) {
  int t = blockIdx.x * 256 + threadIdx.x;
  if (t < 512) ssq[t] = 0.0f;
  if (t < 8192) { wqb[t] = f2bf(Wq[t]); wkb[t] = f2bf(Wk[t]); }
  int tv = t - 8192;
  if (tv >= 0 && tv < 65536) wvb[tv] = f2bf(Wv[tv]);
}

// ---------------- kernel 1: QKV GEMM, channel-split x2 ----------------
__launch_bounds__(256, 4)
__global__ void qkv_kernel(const float* __restrict__ x,
                           const unsigned short* __restrict__ wqb,
                           const unsigned short* __restrict__ wkb,
                           const unsigned short* __restrict__ wvb,
                           const float* __restrict__ bq, const float* __restrict__ bk,
                           const float* __restrict__ bv,
                           unsigned short* __restrict__ qbf, unsigned short* __restrict__ kbf,
                           unsigned short* __restrict__ vbf, float* __restrict__ ssq) {
  int b = blockIdx.x & 7;
  int nblk = (blockIdx.x >> 3) & 63;
  int half = blockIdx.x >> 9;
  int w = threadIdx.x >> 6, lane = threadIdx.x & 63;
  int r = lane & 15, g = lane >> 4;
  int n0 = nblk * 64 + w * 16;

  short8 xf[8];
  #pragma unroll
  for (int ks = 0; ks < 8; ++ks) {
    #pragma unroll
    for (int j = 0; j < 8; ++j) {
      int c = ks * 32 + g * 8 + j;
      float v = x[((size_t)(b * C_ + c) << 12) + n0 + r];
      ((unsigned short*)&xf[ks])[j] = f2bf(v);
    }
  }
  floatx4 zero = {0.f, 0.f, 0.f, 0.f};

  #pragma unroll 2
  for (int ot = half * 8; ot < half * 8 + 8; ++ot) {
    floatx4 acc = zero;
    #pragma unroll
    for (int ks = 0; ks < 8; ++ks) {
      short8 af = *(const short8*)&wvb[(ot * 16 + r) * 256 + ks * 32 + g * 8];
      acc = __builtin_amdgcn_mfma_f32_16x16x32_bf16(af, xf[ks], acc, 0, 0, 0);
    }
    #pragma unroll
    for (int rr = 0; rr < 4; ++rr) {
      int oc = ot * 16 + g * 4 + rr;
      vbf[((size_t)(b * C_ + oc) << 12) + n0 + r] = f2bf(acc[rr] + bv[oc]);
    }
  }
  const unsigned short* wb = half ? wkb : wqb;
  const float* bias = half ? bk : bq;
  unsigned short* dst = half ? kbf : qbf;
  int sbase = half ? 256 : 0;
  #pragma unroll 2
  for (int ot = 0; ot < 2; ++ot) {
    floatx4 acc = zero;
    #pragma unroll
    for (int ks = 0; ks < 8; ++ks) {
      short8 af = *(const short8*)&wb[(ot * 16 + r) * 256 + ks * 32 + g * 8];
      acc = __builtin_amdgcn_mfma_f32_16x16x32_bf16(af, xf[ks], acc, 0, 0, 0);
    }
    #pragma unroll
    for (int rr = 0; rr < 4; ++rr) {
      int oc = ot * 16 + g * 4 + rr;
      float val = acc[rr] + bias[oc];
      dst[(size_t)(b * N_ + n0 + r) * 32 + oc] = f2bf(val);
      float s = val * val;
      s += __shfl_xor(s, 1);
      s += __shfl_xor(s, 2);
      s += __shfl_xor(s, 4);
      s += __shfl_xor(s, 8);
      if (r == 0) atomicAdd(&ssq[sbase + b * 32 + oc], s);
    }
  }
}

// ---------------- kernel 2: in-place scale of Q,K ----------------
__global__ void scale_kernel(unsigned int* __restrict__ qw, unsigned int* __restrict__ kw,
                             const float* __restrict__ ssq, const float* __restrict__ temp) {
  int tt = blockIdx.x * 256 + threadIdx.x;
  int is_k = tt >> 19;
  int idx = tt & 0x7FFFF;
  unsigned int* ptr = is_k ? kw : qw;
  unsigned int v = ptr[idx];
  int c0 = (idx & 15) * 2;
  int b = idx >> 16;
  float invt = is_k ? 1.0f : LOG2E / (temp[0] + 1e-6f);
  float s0 = ssq[is_k * 256 + b * 32 + c0];
  float s1 = ssq[is_k * 256 + b * 32 + c0 + 1];
  float sc0 = invt / fmaxf(sqrtf(s0), 1e-12f);
  float sc1 = invt / fmaxf(sqrtf(s1), 1e-12f);
  unsigned short lo = f2bf(bf2f((unsigned short)(v & 0xFFFFu)) * sc0);
  unsigned short hi = f2bf(bf2f((unsigned short)(v >> 16)) * sc1);
  ptr[idx] = ((unsigned int)hi << 16) | lo;
}

// ---------------- kernel 3: 32x32-MFMA attention, in-register P ----------------
// Block: m=128 rows, 512 thr (8 waves = 4 m-slices x 2 cv-halves). Grid 256 = 1 block/CU,
// batch b = blockIdx&7 aligns with XCD round-robin (V slice L2-affine).
// Per 32-n tile: QK via 2x mfma_32x32x16 (K from LDS); P stays in registers;
// PV B-operand built with 4 pk2 + 2 v_permlane32_swap_b32 per k16-step (no LDS for P).
// V (20KB padded) + K (2.5KB) double-buffered in LDS, reg-staged one tile ahead;
// ONE barrier per tile. Padded row stride 80B: bijective (round-7 XOR swizzle
// overflowed the 64B row and clobbered rows), 16B-aligned b128, bank-floor access.
__launch_bounds__(512, 2)
__global__ void attn_kernel(const unsigned short* __restrict__ qbf,
                            const unsigned short* __restrict__ kbf,
                            const unsigned short* __restrict__ vbf,
                            const float* __restrict__ x, const float* __restrict__ gamma,
                            float* __restrict__ out) {
  __shared__ __align__(16) char Vt[2][256 * VSTRIDE];   // [buf][256 cv][32 n + pad]
  __shared__ __align__(16) char Kt[2][32 * VSTRIDE];    // [buf][32 n][32 ch + pad]
  int b = blockIdx.x & 7, mblk = blockIdx.x >> 3;       // mblk in [0,32)
  int tid = threadIdx.x;
  int w = tid >> 6, lane = tid & 63, c = lane & 31, h = lane >> 5;
  int ms = w & 3, cvh = w >> 2;
  const unsigned short* qb = qbf + (size_t)b * N_ * 32;
  const unsigned short* kb = kbf + (size_t)b * N_ * 32;
  const unsigned short* vb = vbf + (size_t)b * C_ * N_;
  int mrow = mblk * 128 + ms * 32 + c;                  // this lane's global m (column)
  short8 qf0 = *(const short8*)&qb[mrow * 32 + h * 8];
  short8 qf1 = *(const short8*)&qb[mrow * 32 + 16 + h * 8];
  int tdiag = mblk * 4 + ms;

  // staging: V 16KB by all 512 thr (32B each), K 2KB by tid<128 (16B each)
  int vrow = tid >> 1, vhalf = tid & 1;
  const unsigned short* vsrc_base = vb + (size_t)vrow * N_ + vhalf * 16;
  int krow = tid >> 2, kq = tid & 3;
  const unsigned short* ksrc_base = kb + (size_t)krow * 32 + kq * 8;
  int vwr0 = vrow * VSTRIDE + vhalf * 32;
  int vwr1 = vwr0 + 16;
  int kwr = krow * VSTRIDE + kq * 16;

  floatx16 zero16 = {0,0,0,0,0,0,0,0,0,0,0,0,0,0,0,0};
  floatx16 acc[4] = {zero16, zero16, zero16, zero16};   // [cvt] D[cv 32][m 32]
  float Lp = 0.0f;
  short8 sv0, sv1, sk;

  auto issue = [&](int t) {
    const unsigned short* vs = vsrc_base + t * 32;
    sv0 = *(const short8*)vs;
    sv1 = *(const short8*)(vs + 8);
    if (tid < 128) sk = *(const short8*)(ksrc_base + (size_t)t * 1024);
  };
  auto commit = [&](int buf) {
    *(short8*)(Vt[buf] + vwr0) = sv0;
    *(short8*)(Vt[buf] + vwr1) = sv1;
    if (tid < 128) *(short8*)(Kt[buf] + kwr) = sk;
  };
  auto compute = [&](int t, int buf) {
    const char* Kb = Kt[buf];
    const char* Vb = Vt[buf];
    short8 kf0 = *(const short8*)(Kb + c * VSTRIDE + h * 16);
    short8 kf1 = *(const short8*)(Kb + c * VSTRIDE + 32 + h * 16);
    floatx16 s = __builtin_amdgcn_mfma_f32_32x32x16_bf16(kf0, qf0, zero16, 0, 0, 0);
    s = __builtin_amdgcn_mfma_f32_32x32x16_bf16(kf1, qf1, s, 0, 0, 0);
    if (t == tdiag && ((c >> 2) & 1) == h)              // +I where global n == m
      s[(c & 3) | ((c >> 3) << 2)] += LOG2E;
    float p[16];
    float ls = 0.0f;
    #pragma unroll
    for (int i = 0; i < 16; ++i) {
      p[i] = __builtin_amdgcn_exp2f(s[i] - 2.0f * LOG2E);
      ls += p[i];
    }
    Lp += ls;
    #pragma unroll
    for (int t16 = 0; t16 < 2; ++t16) {
      // own n-locals (rel 16t16): h=0 lanes {0-3,8-11}, h=1 lanes {4-7,12-15}
      unsigned int q0 = pk2(p[8*t16+0], p[8*t16+1]);    // n 0,1 (h=0) / 4,5 (h=1)
      unsigned int q1 = pk2(p[8*t16+2], p[8*t16+3]);    // n 2,3 / 6,7
      unsigned int q2 = pk2(p[8*t16+4], p[8*t16+5]);    // n 8,9 / 12,13
      unsigned int q3 = pk2(p[8*t16+6], p[8*t16+7]);    // n 10,11 / 14,15
      // swap(vdst,vsrc): vdst[0:31] <-> vsrc[32:63].
      // After swap(q2,q0): lo lanes q2 = partner q0 (n 4,5); hi lanes q0 = partner q2 (n 8,9).
      asm volatile("v_permlane32_swap_b32 %0, %1" : "+v"(q2), "+v"(q0));
      asm volatile("v_permlane32_swap_b32 %0, %1" : "+v"(q3), "+v"(q1));
      // B words k=h*8+j: h=0 -> n 0..7 = [q0,q1,q2,q3]; h=1 -> n 8..15 = [q0,q1,q2,q3]
      union { unsigned int u[4]; short8 s8; } bf;
      bf.u[0] = q0; bf.u[1] = q1; bf.u[2] = q2; bf.u[3] = q3;
      #pragma unroll
      for (int cvt = 0; cvt < 4; ++cvt) {
        int R = cvh * 128 + cvt * 32 + c;
        short8 af = *(const short8*)(Vb + R * VSTRIDE + t16 * 32 + h * 16);
        acc[cvt] = __builtin_amdgcn_mfma_f32_32x32x16_bf16(af, bf.s8, acc[cvt], 0, 0, 0);
      }
    }
  };

  issue(0); commit(0); __syncthreads();
  issue(1);
  #pragma unroll 1
  for (int t = 0; t < 128; ++t) {
    int cur = t & 1;
    compute(t, cur);
    if (t + 1 < 128) commit(cur ^ 1);
    __syncthreads();
    if (t + 2 < 128) issue(t + 2);
  }

  // denominator: lane holds half the n-sum for column m; partner (lane^32) has the rest
  Lp += __shfl_xor(Lp, 32);
  float linv = 1.0f / Lp;
  float gam = gamma[0];
  #pragma unroll
  for (int cvt = 0; cvt < 4; ++cvt)
    #pragma unroll
    for (int i = 0; i < 16; ++i) {
      int cv = cvh * 128 + cvt * 32 + (i & 3) + 8 * (i >> 2) + 4 * h;
      size_t idx = ((size_t)(b * C_ + cv) << 12) + mrow;
      out[idx] = gam * acc[cvt][i] * linv + x[idx];
    }
}

extern "C" void kernel_launch(void* const* d_in, const int* in_sizes, int n_in,
                              void* d_out, int out_size, void* d_ws, size_t ws_size,
                              hipStream_t stream) {
  (void)in_sizes; (void)n_in; (void)out_size; (void)ws_size;
  const float* x    = (const float*)d_in[0];
  const float* Wq   = (const float*)d_in[1];
  const float* bq   = (const float*)d_in[2];
  const float* Wk   = (const float*)d_in[3];
  const float* bk   = (const float*)d_in[4];
  const float* Wv   = (const float*)d_in[5];
  const float* bv   = (const float*)d_in[6];
  const float* gam  = (const float*)d_in[7];
  const float* temp = (const float*)d_in[8];
  float* out = (float*)d_out;

  char* ws = (char*)d_ws;
  unsigned short* vbf = (unsigned short*)ws;                       // 16 MB
  unsigned short* qbf = (unsigned short*)(ws + (16u << 20));       // 2 MB
  unsigned short* kbf = (unsigned short*)(ws + (18u << 20));       // 2 MB
  unsigned short* wqb = (unsigned short*)(ws + (20u << 20));       // 16 KB
  unsigned short* wkb = wqb + 8192;                                // 16 KB
  unsigned short* wvb = wkb + 8192;                                // 128 KB
  float* ssq = (float*)(wvb + 65536);                              // 2 KB

  prep_kernel<<<dim3(288), dim3(256), 0, stream>>>(Wq, Wk, Wv, wqb, wkb, wvb, ssq);
  qkv_kernel<<<dim3(1024), dim3(256), 0, stream>>>(x, wqb, wkb, wvb, bq, bk, bv, qbf, kbf, vbf, ssq);
  scale_kernel<<<dim3(4096), dim3(256), 0, stream>>>((unsigned int*)qbf, (unsigned int*)kbf, ssq, temp);
  attn_kernel<<<dim3(256), dim3(512), 0, stream>>>(qbf, kbf, vbf, x, gam, out);
}